// Round 12
// baseline (263.298 us; speedup 1.0000x reference)
//
#include <hip/hip_runtime.h>
#include <hip/hip_fp16.h>

#define HDIM 64
#define INDIM 128
#define OUTDIM 32
#define CAP 64        // padded-CSR capacity per node; deg ~ Poisson(16)
#define BNODES 128    // nodes per bucket (bucket = dst >> 7)
#define EPB 4096      // edges per block in pass A
#define BCAP 2304     // per-bucket edge capacity (mean 2046, +5.7 sigma)
#define SRCBITS 17    // src ids < 2^17 (n <= 131072)

// ---------------- pass A: bin edges by dst-bucket ----------------
__global__ __launch_bounds__(256) void bin_edges(const int* __restrict__ dst,
                                                 const int* __restrict__ src,
                                                 int* __restrict__ gcur,
                                                 int* __restrict__ binned,
                                                 int e, int nb) {
    __shared__ int hist[1024];
    __shared__ int base[1024];
    for (int i = threadIdx.x; i < nb; i += 256) hist[i] = 0;
    __syncthreads();

    int e0 = blockIdx.x * EPB + (int)threadIdx.x * 16;
    int d[16], s[16], p[16];
    bool vec_ok = ((e & 3) == 0);
    #pragma unroll
    for (int k = 0; k < 4; k++) {
        int i = e0 + 4 * k;
        if (vec_ok && i + 4 <= e) {
            int4 d4 = *(const int4*)(dst + i);
            int4 s4 = *(const int4*)(src + i);
            d[4*k+0] = d4.x; d[4*k+1] = d4.y; d[4*k+2] = d4.z; d[4*k+3] = d4.w;
            s[4*k+0] = s4.x; s[4*k+1] = s4.y; s[4*k+2] = s4.z; s[4*k+3] = s4.w;
        } else {
            #pragma unroll
            for (int j = 0; j < 4; j++) {
                int ii = i + j;
                if (ii < e) { d[4*k+j] = dst[ii]; s[4*k+j] = src[ii]; }
                else        { d[4*k+j] = -1;      s[4*k+j] = 0; }
            }
        }
    }
    #pragma unroll
    for (int k = 0; k < 16; k++)
        if (d[k] >= 0) p[k] = atomicAdd(&hist[d[k] >> 7], 1);
    __syncthreads();
    for (int b = threadIdx.x; b < nb; b += 256) {
        int h = hist[b];
        base[b] = h ? atomicAdd(&gcur[b], h) : 0;
    }
    __syncthreads();
    #pragma unroll
    for (int k = 0; k < 16; k++) {
        if (d[k] < 0) continue;
        int b = d[k] >> 7;
        int pos = base[b] + p[k];
        if (pos < BCAP)
            binned[(size_t)b * BCAP + pos] = ((d[k] & (BNODES - 1)) << SRCBITS) | s[k];
    }
}

// ---------------- pass B: per-bucket padded CSR built in LDS ----------------
__global__ __launch_bounds__(256) void build_csr(const int* __restrict__ gcur,
                                                 const int* __restrict__ binned,
                                                 int* __restrict__ cnt,
                                                 float* __restrict__ rs,
                                                 int* __restrict__ csr, int n) {
    __shared__ int lcsr[BNODES * CAP];   // 32 KiB
    __shared__ int lcnt[BNODES];
    if (threadIdx.x < BNODES) lcnt[threadIdx.x] = 0;
    __syncthreads();
    int b = blockIdx.x;
    int m = min(gcur[b], BCAP);
    const int* be = binned + (size_t)b * BCAP;
    for (int i = threadIdx.x; i < m; i += 256) {
        int v = be[i];
        int ld = v >> SRCBITS;
        int pos = atomicAdd(&lcnt[ld], 1);
        if (pos < CAP) lcsr[ld * CAP + pos] = v & ((1 << SRCBITS) - 1);
    }
    __syncthreads();
    int4* gout = (int4*)(csr + (size_t)b * (BNODES * CAP));
    const int4* lin = (const int4*)lcsr;
    #pragma unroll 2
    for (int i = threadIdx.x; i < BNODES * CAP / 4; i += 256) gout[i] = lin[i];
    int node = b * BNODES + (int)threadIdx.x;
    if (threadIdx.x < BNODES && node < n) {
        int c = lcnt[threadIdx.x];
        cnt[node] = c;
        rs[node] = rsqrtf((float)c + 1.0f);
    }
}

// ---------------- register-blocked node GEMM (input layer): C = A @ W ------
// Unchanged from R11 (proven: VGPR=36, no launch-bounds min-blocks arg —
// R10 showed hipcc treats it as CUDA min-BLOCKS/CU and spills).
template<int K, int N, int BM, int BLOCK, bool RELU, bool EMIT16>
__global__ __launch_bounds__(BLOCK) void gemm_node(const float* __restrict__ A,
                                                   const float* __restrict__ W,
                                                   float* __restrict__ C,
                                                   __half* __restrict__ C16,
                                                   const float* __restrict__ rs,
                                                   int n) {
    constexpr int TX = N / 8;
    constexpr int TY = BLOCK / TX;
    constexpr int R = BM / TY;
    static_assert(BM % TY == 0, "");
    __shared__ float w[K * N];
    for (int i = threadIdx.x; i < K * N; i += BLOCK) w[i] = W[i];
    __syncthreads();
    int tx = (int)threadIdx.x % TX;
    int ty = (int)threadIdx.x / TX;
    int base = blockIdx.x * BM + ty * R;

    const float* pa[R];
    #pragma unroll
    for (int r = 0; r < R; r++) {
        int row = base + r;
        row = row < n ? row : n - 1;
        pa[r] = A + (size_t)row * K;
    }

    float acc[R][8];
    #pragma unroll
    for (int r = 0; r < R; r++)
        #pragma unroll
        for (int i = 0; i < 8; i++) acc[r][i] = 0.f;

    #pragma unroll 2
    for (int k = 0; k < K; k += 4) {
        float4 a4[R];
        #pragma unroll
        for (int r = 0; r < R; r++) a4[r] = *(const float4*)(pa[r] + k);
        #pragma unroll
        for (int kk = 0; kk < 4; kk++) {
            float4 b0 = *(const float4*)(w + (k + kk) * N + tx * 8);
            float4 b1 = *(const float4*)(w + (k + kk) * N + tx * 8 + 4);
            #pragma unroll
            for (int r = 0; r < R; r++) {
                float av = (kk == 0) ? a4[r].x : (kk == 1) ? a4[r].y
                         : (kk == 2) ? a4[r].z : a4[r].w;
                acc[r][0] += av * b0.x; acc[r][1] += av * b0.y;
                acc[r][2] += av * b0.z; acc[r][3] += av * b0.w;
                acc[r][4] += av * b1.x; acc[r][5] += av * b1.y;
                acc[r][6] += av * b1.z; acc[r][7] += av * b1.w;
            }
        }
    }

    #pragma unroll
    for (int r = 0; r < R; r++) {
        int node = base + r;
        if (node >= n) continue;
        float4 o0, o1;
        o0.x = RELU ? fmaxf(acc[r][0], 0.f) : acc[r][0];
        o0.y = RELU ? fmaxf(acc[r][1], 0.f) : acc[r][1];
        o0.z = RELU ? fmaxf(acc[r][2], 0.f) : acc[r][2];
        o0.w = RELU ? fmaxf(acc[r][3], 0.f) : acc[r][3];
        o1.x = RELU ? fmaxf(acc[r][4], 0.f) : acc[r][4];
        o1.y = RELU ? fmaxf(acc[r][5], 0.f) : acc[r][5];
        o1.z = RELU ? fmaxf(acc[r][6], 0.f) : acc[r][6];
        o1.w = RELU ? fmaxf(acc[r][7], 0.f) : acc[r][7];
        *(float4*)(C + (size_t)node * N + tx * 8) = o0;
        *(float4*)(C + (size_t)node * N + tx * 8 + 4) = o1;
        if (EMIT16) {
            float rsv = rs[node];
            __half2 p0 = __floats2half2_rn(rsv * o0.x, rsv * o0.y);
            __half2 p1 = __floats2half2_rn(rsv * o0.z, rsv * o0.w);
            __half2 p2 = __floats2half2_rn(rsv * o1.x, rsv * o1.y);
            __half2 p3 = __floats2half2_rn(rsv * o1.z, rsv * o1.w);
            uint4 pk;
            pk.x = *(unsigned int*)&p0;
            pk.y = *(unsigned int*)&p1;
            pk.z = *(unsigned int*)&p2;
            pk.w = *(unsigned int*)&p3;
            *(uint4*)(C16 + (size_t)node * N + tx * 8) = pk;
        }
    }
}

// ---------------- fused layer: gather + skip + GEMM (+ out-GEMM for L=1) ----
// Wave per node (grid-stride). Gather is HBM-bound (R11: 2.4 TB/s, VALU 47%)
// so the in-wave W-multiply rides free. Row staged in wave-private LDS
// (broadcast ds_read_b128); W_T stride-68 rows => 16B-aligned, even 8
// dwords/bank per wave access (bank-conflict-free rate).
// L=0: h' = relu(arow @ W); writes h (in-place, own row) + h16out (rs-scaled).
// L=1: also out = h' @ Wout via second LDS round + shfl_xor(32) split-k.
template<int L>
__global__ __launch_bounds__(256) void layer_fused(
    const __half* __restrict__ h16in, float* __restrict__ h,
    __half* __restrict__ h16out, float* __restrict__ outp,
    const float* __restrict__ Wlayer, const float* __restrict__ Wout,
    const int* __restrict__ cnt, const int* __restrict__ csr,
    const float* __restrict__ rs, int n)
{
    __shared__ __align__(16) float wT[HDIM * 68];                  // 17.4 KB
    __shared__ __align__(16) float woT[(L == 1 ? OUTDIM : 1) * 68];
    __shared__ __align__(16) float rowbuf[4][HDIM];                // 1 KB
    __shared__ __align__(16) float rowbuf2[(L == 1 ? 4 : 1)][HDIM];

    for (int i = threadIdx.x; i < HDIM * HDIM; i += 256) {
        int k = i >> 6, f = i & 63;
        wT[f * 68 + k] = Wlayer[i];
    }
    if (L == 1) {
        for (int i = threadIdx.x; i < HDIM * OUTDIM; i += 256) {
            int f = i >> 5, g = i & 31;
            woT[g * 68 + f] = Wout[i];
        }
    }
    __syncthreads();

    int wave = threadIdx.x >> 6, lane = threadIdx.x & 63;
    int grp = lane >> 4, gl = lane & 15;

    for (int node = blockIdx.x * 4 + wave; node < n; node += gridDim.x * 4) {
        // ---- gather: arow_partial = sum h16in[s] (pre-scaled by rs[s]) ----
        int c = min(cnt[node], CAP);
        int sl = 0;
        if (lane < c) sl = csr[node * CAP + lane];
        float4 acc0 = make_float4(0.f, 0.f, 0.f, 0.f);
        float4 acc1 = make_float4(0.f, 0.f, 0.f, 0.f);
        int trips = (c + 3) >> 2;
        int i = 0;
        for (; i + 2 <= trips; i += 2) {
            int t0 = 4 * i + grp, t1 = t0 + 4;
            float w0 = (t0 < c) ? 1.f : 0.f;
            float w1 = (t1 < c) ? 1.f : 0.f;
            int u0 = min(t0, c - 1);
            int u1 = min(t1, c - 1);
            int s0 = __shfl(sl, u0);
            int s1 = __shfl(sl, u1);
            uint2 q0 = ((const uint2*)(h16in + (size_t)s0 * HDIM))[gl];
            uint2 q1 = ((const uint2*)(h16in + (size_t)s1 * HDIM))[gl];
            float2 f0a = __half22float2(*(__half2*)&q0.x);
            float2 f0b = __half22float2(*(__half2*)&q0.y);
            float2 f1a = __half22float2(*(__half2*)&q1.x);
            float2 f1b = __half22float2(*(__half2*)&q1.y);
            acc0.x += w0 * f0a.x; acc0.y += w0 * f0a.y;
            acc0.z += w0 * f0b.x; acc0.w += w0 * f0b.y;
            acc1.x += w1 * f1a.x; acc1.y += w1 * f1a.y;
            acc1.z += w1 * f1b.x; acc1.w += w1 * f1b.y;
        }
        if (i < trips) {
            int t = 4 * i + grp;
            float wv = (t < c) ? 1.f : 0.f;
            int u = min(t, c - 1);
            int s = __shfl(sl, u);
            uint2 q = ((const uint2*)(h16in + (size_t)s * HDIM))[gl];
            float2 fa = __half22float2(*(__half2*)&q.x);
            float2 fb = __half22float2(*(__half2*)&q.y);
            acc0.x += wv * fa.x; acc0.y += wv * fa.y;
            acc0.z += wv * fb.x; acc0.w += wv * fb.y;
        }
        acc0.x += acc1.x; acc0.y += acc1.y; acc0.z += acc1.z; acc0.w += acc1.w;
        #pragma unroll
        for (int m = 16; m < 64; m <<= 1) {
            acc0.x += __shfl_xor(acc0.x, m);
            acc0.y += __shfl_xor(acc0.y, m);
            acc0.z += __shfl_xor(acc0.z, m);
            acc0.w += __shfl_xor(acc0.w, m);
        }
        // ---- scale + skip; stage row in wave-private LDS ----
        float rsd = rs[node];
        if (grp == 0) {
            float4 sk = ((const float4*)(h + (size_t)node * HDIM))[gl];
            acc0.x = acc0.x * rsd + sk.x;
            acc0.y = acc0.y * rsd + sk.y;
            acc0.z = acc0.z * rsd + sk.z;
            acc0.w = acc0.w * rsd + sk.w;
            *(float4*)&rowbuf[wave][gl * 4] = acc0;
        }
        // ---- h' [f=lane] = relu(arow . W[:,lane]) ----
        float4 m4 = make_float4(0.f, 0.f, 0.f, 0.f);
        #pragma unroll
        for (int kg = 0; kg < 16; kg++) {
            float4 rv = *(const float4*)&rowbuf[wave][kg * 4];      // broadcast
            float4 wv = *(const float4*)&wT[lane * 68 + kg * 4];
            m4.x += rv.x * wv.x; m4.y += rv.y * wv.y;
            m4.z += rv.z * wv.z; m4.w += rv.w * wv.w;
        }
        float t = fmaxf(m4.x + m4.y + m4.z + m4.w, 0.f);
        if (L == 0) {
            h[(size_t)node * HDIM + lane] = t;
            h16out[(size_t)node * HDIM + lane] = __float2half(rsd * t);
        } else {
            // ---- out[g] = h' . Wout[:,g], split-k over wave halves ----
            rowbuf2[wave][lane] = t;
            int g = lane & 31, half = lane >> 5;
            float4 o4 = make_float4(0.f, 0.f, 0.f, 0.f);
            #pragma unroll
            for (int kg = 0; kg < 8; kg++) {
                float4 rv = *(const float4*)&rowbuf2[wave][half * 32 + kg * 4];
                float4 wv = *(const float4*)&woT[g * 68 + half * 32 + kg * 4];
                o4.x += rv.x * wv.x; o4.y += rv.y * wv.y;
                o4.z += rv.z * wv.z; o4.w += rv.w * wv.w;
            }
            float t2 = o4.x + o4.y + o4.z + o4.w;
            t2 += __shfl_xor(t2, 32);
            if (lane < 32) outp[(size_t)node * OUTDIM + lane] = t2;
        }
    }
}

extern "C" void kernel_launch(void* const* d_in, const int* in_sizes, int n_in,
                              void* d_out, int out_size, void* d_ws, size_t ws_size,
                              hipStream_t stream) {
    const float* x    = (const float*)d_in[0];
    const int*   ei   = (const int*)d_in[1];
    const float* Win  = (const float*)d_in[2];
    const float* Wl   = (const float*)d_in[3];
    const float* Wout = (const float*)d_in[4];
    float* out = (float*)d_out;

    int n = in_sizes[0] / INDIM;   // 100000
    int e = in_sizes[1] / 2;       // 1600000
    const int* dst = ei;           // edge_index[0]
    const int* src = ei + e;       // edge_index[1]

    int nb = (n + BNODES - 1) / BNODES;   // 782 buckets

    // workspace: gcur | cnt | rs | binned | csr_pad | h | h16a | h16b
    char* w = (char*)d_ws;
    int* gcur = (int*)w;      w += 1024 * 4;
    int* cnt = (int*)w;       w += (size_t)n * 4;
    float* rs = (float*)w;    w += (size_t)n * 4;
    w = (char*)(((uintptr_t)w + 255) & ~(uintptr_t)255);
    int* binned = (int*)w;    w += (size_t)nb * BCAP * 4;          // 7.2 MB
    int* csr = (int*)w;       w += (size_t)nb * BNODES * CAP * 4;  // 25.6 MB
    float* h = (float*)w;     w += (size_t)n * HDIM * 4;           // 25.6 MB
    __half* h16a = (__half*)w; w += (size_t)n * HDIM * 2;          // 12.8 MB
    __half* h16b = (__half*)w; w += (size_t)n * HDIM * 2;          // 12.8 MB

    hipMemsetAsync(gcur, 0, 1024 * 4, stream);

    // two-phase padded-CSR build
    int ablocks = (e + EPB - 1) / EPB;    // 391
    bin_edges<<<ablocks, 256, 0, stream>>>(dst, src, gcur, binned, e, nb);
    build_csr<<<nb, 256, 0, stream>>>(gcur, binned, cnt, rs, csr, n);

    int g128 = (n + 127) / 128;   // 782 blocks at BM=128
    // h = x @ W_in  (+ rs-scaled fp16 shadow h16a)
    gemm_node<INDIM, HDIM, 128, 512, false, true><<<g128, 512, 0, stream>>>(
        x, Win, h, h16a, rs, n);

    // fused layers
    layer_fused<0><<<2048, 256, 0, stream>>>(h16a, h, h16b, nullptr,
                                             Wl, nullptr, cnt, csr, rs, n);
    layer_fused<1><<<1280, 256, 0, stream>>>(h16b, h, nullptr, out,
                                             Wl + (size_t)HDIM * HDIM, Wout,
                                             cnt, csr, rs, n);
}

// Round 13
// 200.045 us; speedup vs baseline: 1.3162x; 1.3162x over previous
//
#include <hip/hip_runtime.h>
#include <hip/hip_fp16.h>

#define HDIM 64
#define INDIM 128
#define OUTDIM 32
#define CAP 64        // padded-CSR capacity per node; deg ~ Poisson(16)
#define BNODES 128    // nodes per bucket (bucket = dst >> 7)
#define EPB 4096      // edges per block in pass A
#define BCAP 2304     // per-bucket edge capacity (mean 2046, +5.7 sigma)
#define SRCBITS 17    // src ids < 2^17 (n <= 131072)

// ---------------- pass A: bin edges by dst-bucket ----------------
__global__ __launch_bounds__(256) void bin_edges(const int* __restrict__ dst,
                                                 const int* __restrict__ src,
                                                 int* __restrict__ gcur,
                                                 int* __restrict__ binned,
                                                 int e, int nb) {
    __shared__ int hist[1024];
    __shared__ int base[1024];
    for (int i = threadIdx.x; i < nb; i += 256) hist[i] = 0;
    __syncthreads();

    int e0 = blockIdx.x * EPB + (int)threadIdx.x * 16;
    int d[16], s[16], p[16];
    bool vec_ok = ((e & 3) == 0);
    #pragma unroll
    for (int k = 0; k < 4; k++) {
        int i = e0 + 4 * k;
        if (vec_ok && i + 4 <= e) {
            int4 d4 = *(const int4*)(dst + i);
            int4 s4 = *(const int4*)(src + i);
            d[4*k+0] = d4.x; d[4*k+1] = d4.y; d[4*k+2] = d4.z; d[4*k+3] = d4.w;
            s[4*k+0] = s4.x; s[4*k+1] = s4.y; s[4*k+2] = s4.z; s[4*k+3] = s4.w;
        } else {
            #pragma unroll
            for (int j = 0; j < 4; j++) {
                int ii = i + j;
                if (ii < e) { d[4*k+j] = dst[ii]; s[4*k+j] = src[ii]; }
                else        { d[4*k+j] = -1;      s[4*k+j] = 0; }
            }
        }
    }
    #pragma unroll
    for (int k = 0; k < 16; k++)
        if (d[k] >= 0) p[k] = atomicAdd(&hist[d[k] >> 7], 1);
    __syncthreads();
    for (int b = threadIdx.x; b < nb; b += 256) {
        int h = hist[b];
        base[b] = h ? atomicAdd(&gcur[b], h) : 0;
    }
    __syncthreads();
    #pragma unroll
    for (int k = 0; k < 16; k++) {
        if (d[k] < 0) continue;
        int b = d[k] >> 7;
        int pos = base[b] + p[k];
        if (pos < BCAP)
            binned[(size_t)b * BCAP + pos] = ((d[k] & (BNODES - 1)) << SRCBITS) | s[k];
    }
}

// ---------------- pass B: per-bucket padded CSR built in LDS ----------------
__global__ __launch_bounds__(256) void build_csr(const int* __restrict__ gcur,
                                                 const int* __restrict__ binned,
                                                 int* __restrict__ cnt,
                                                 float* __restrict__ rs,
                                                 int* __restrict__ csr, int n) {
    __shared__ int lcsr[BNODES * CAP];   // 32 KiB
    __shared__ int lcnt[BNODES];
    if (threadIdx.x < BNODES) lcnt[threadIdx.x] = 0;
    __syncthreads();
    int b = blockIdx.x;
    int m = min(gcur[b], BCAP);
    const int* be = binned + (size_t)b * BCAP;
    for (int i = threadIdx.x; i < m; i += 256) {
        int v = be[i];
        int ld = v >> SRCBITS;
        int pos = atomicAdd(&lcnt[ld], 1);
        if (pos < CAP) lcsr[ld * CAP + pos] = v & ((1 << SRCBITS) - 1);
    }
    __syncthreads();
    int4* gout = (int4*)(csr + (size_t)b * (BNODES * CAP));
    const int4* lin = (const int4*)lcsr;
    #pragma unroll 2
    for (int i = threadIdx.x; i < BNODES * CAP / 4; i += 256) gout[i] = lin[i];
    int node = b * BNODES + (int)threadIdx.x;
    if (threadIdx.x < BNODES && node < n) {
        int c = lcnt[threadIdx.x];
        cnt[node] = c;
        rs[node] = rsqrtf((float)c + 1.0f);
    }
}

// ---------------- register-blocked node GEMM: C = A @ W ----------------
// R=2 rows/thread; NO launch-bounds min-blocks arg (R10: hipcc treats it as
// CUDA min-BLOCKS/CU -> VGPR=32 cap -> scratch spill disaster).
// unroll 4: deeper global-load pipeline (gemm_in is L3-latency-bound).
template<int K, int N, int BM, int BLOCK, bool RELU, bool EMIT16>
__global__ __launch_bounds__(BLOCK) void gemm_node(const float* __restrict__ A,
                                                   const float* __restrict__ W,
                                                   float* __restrict__ C,
                                                   __half* __restrict__ C16,
                                                   const float* __restrict__ rs,
                                                   int n) {
    constexpr int TX = N / 8;
    constexpr int TY = BLOCK / TX;
    constexpr int R = BM / TY;
    static_assert(BM % TY == 0, "");
    __shared__ float w[K * N];
    for (int i = threadIdx.x; i < K * N; i += BLOCK) w[i] = W[i];
    __syncthreads();
    int tx = (int)threadIdx.x % TX;
    int ty = (int)threadIdx.x / TX;
    int base = blockIdx.x * BM + ty * R;

    const float* pa[R];
    #pragma unroll
    for (int r = 0; r < R; r++) {
        int row = base + r;
        row = row < n ? row : n - 1;      // clamp: loads always safe
        pa[r] = A + (size_t)row * K;
    }

    float acc[R][8];
    #pragma unroll
    for (int r = 0; r < R; r++)
        #pragma unroll
        for (int i = 0; i < 8; i++) acc[r][i] = 0.f;

    #pragma unroll 4
    for (int k = 0; k < K; k += 4) {
        float4 a4[R];
        #pragma unroll
        for (int r = 0; r < R; r++) a4[r] = *(const float4*)(pa[r] + k);
        #pragma unroll
        for (int kk = 0; kk < 4; kk++) {
            float4 b0 = *(const float4*)(w + (k + kk) * N + tx * 8);
            float4 b1 = *(const float4*)(w + (k + kk) * N + tx * 8 + 4);
            #pragma unroll
            for (int r = 0; r < R; r++) {
                float av = (kk == 0) ? a4[r].x : (kk == 1) ? a4[r].y
                         : (kk == 2) ? a4[r].z : a4[r].w;
                acc[r][0] += av * b0.x; acc[r][1] += av * b0.y;
                acc[r][2] += av * b0.z; acc[r][3] += av * b0.w;
                acc[r][4] += av * b1.x; acc[r][5] += av * b1.y;
                acc[r][6] += av * b1.z; acc[r][7] += av * b1.w;
            }
        }
    }

    #pragma unroll
    for (int r = 0; r < R; r++) {
        int node = base + r;
        if (node >= n) continue;
        float4 o0, o1;
        o0.x = RELU ? fmaxf(acc[r][0], 0.f) : acc[r][0];
        o0.y = RELU ? fmaxf(acc[r][1], 0.f) : acc[r][1];
        o0.z = RELU ? fmaxf(acc[r][2], 0.f) : acc[r][2];
        o0.w = RELU ? fmaxf(acc[r][3], 0.f) : acc[r][3];
        o1.x = RELU ? fmaxf(acc[r][4], 0.f) : acc[r][4];
        o1.y = RELU ? fmaxf(acc[r][5], 0.f) : acc[r][5];
        o1.z = RELU ? fmaxf(acc[r][6], 0.f) : acc[r][6];
        o1.w = RELU ? fmaxf(acc[r][7], 0.f) : acc[r][7];
        *(float4*)(C + (size_t)node * N + tx * 8) = o0;
        *(float4*)(C + (size_t)node * N + tx * 8 + 4) = o1;
        if (EMIT16) {
            float rsv = rs[node];
            __half2 p0 = __floats2half2_rn(rsv * o0.x, rsv * o0.y);
            __half2 p1 = __floats2half2_rn(rsv * o0.z, rsv * o0.w);
            __half2 p2 = __floats2half2_rn(rsv * o1.x, rsv * o1.y);
            __half2 p3 = __floats2half2_rn(rsv * o1.z, rsv * o1.w);
            uint4 pk;
            pk.x = *(unsigned int*)&p0;
            pk.y = *(unsigned int*)&p1;
            pk.z = *(unsigned int*)&p2;
            pk.w = *(unsigned int*)&p3;
            *(uint4*)(C16 + (size_t)node * N + tx * 8) = pk;
        }
    }
}

// ---------------- fused last layer: out = relu(agg @ W2) @ Wout ------------
// Same GEMM body as gemm_node (R=2), but relu rows go to LDS hbuf (stride 68:
// hbuf b32 reads are 16 addrs over 8 bank-groups = 2-way = free; wout b128
// reads hit 4 disjoint bank quads = conflict-free), then a second in-block
// multiply produces out directly. Kills the gemm_out kernel + h write/read.
__global__ __launch_bounds__(512) void gemm_layer_out(const float* __restrict__ A,
                                                      const float* __restrict__ W2,
                                                      const float* __restrict__ Wo,
                                                      float* __restrict__ outp, int n) {
    __shared__ float w[HDIM * HDIM];       // 16 KB
    __shared__ float wo[HDIM * OUTDIM];    // 8 KB
    __shared__ __align__(16) float hbuf[128][68];  // 34.8 KB
    for (int i = threadIdx.x; i < HDIM * HDIM; i += 512) w[i] = W2[i];
    for (int i = threadIdx.x; i < HDIM * OUTDIM; i += 512) wo[i] = Wo[i];
    __syncthreads();
    constexpr int TX = 8, R = 2;
    int tx = (int)threadIdx.x % TX;
    int ty = (int)threadIdx.x / TX;
    int bn = blockIdx.x * 128;
    int base = bn + ty * R;

    const float* pa[R];
    #pragma unroll
    for (int r = 0; r < R; r++) {
        int row = base + r;
        row = row < n ? row : n - 1;
        pa[r] = A + (size_t)row * HDIM;
    }
    float acc[R][8];
    #pragma unroll
    for (int r = 0; r < R; r++)
        #pragma unroll
        for (int i = 0; i < 8; i++) acc[r][i] = 0.f;

    #pragma unroll 4
    for (int k = 0; k < HDIM; k += 4) {
        float4 a4[R];
        #pragma unroll
        for (int r = 0; r < R; r++) a4[r] = *(const float4*)(pa[r] + k);
        #pragma unroll
        for (int kk = 0; kk < 4; kk++) {
            float4 b0 = *(const float4*)(w + (k + kk) * HDIM + tx * 8);
            float4 b1 = *(const float4*)(w + (k + kk) * HDIM + tx * 8 + 4);
            #pragma unroll
            for (int r = 0; r < R; r++) {
                float av = (kk == 0) ? a4[r].x : (kk == 1) ? a4[r].y
                         : (kk == 2) ? a4[r].z : a4[r].w;
                acc[r][0] += av * b0.x; acc[r][1] += av * b0.y;
                acc[r][2] += av * b0.z; acc[r][3] += av * b0.w;
                acc[r][4] += av * b1.x; acc[r][5] += av * b1.y;
                acc[r][6] += av * b1.z; acc[r][7] += av * b1.w;
            }
        }
    }
    // relu rows -> LDS (stride 68)
    #pragma unroll
    for (int r = 0; r < R; r++) {
        int lr = ty * R + r;
        float4 o0, o1;
        o0.x = fmaxf(acc[r][0], 0.f); o0.y = fmaxf(acc[r][1], 0.f);
        o0.z = fmaxf(acc[r][2], 0.f); o0.w = fmaxf(acc[r][3], 0.f);
        o1.x = fmaxf(acc[r][4], 0.f); o1.y = fmaxf(acc[r][5], 0.f);
        o1.z = fmaxf(acc[r][6], 0.f); o1.w = fmaxf(acc[r][7], 0.f);
        *(float4*)&hbuf[lr][tx * 8] = o0;
        *(float4*)&hbuf[lr][tx * 8 + 4] = o1;
    }
    __syncthreads();
    // out[bn+tn][cg*8 .. +7] = hbuf[tn][:] . wo[:, cg*8 .. +7]
    int tn = (int)threadIdx.x >> 2;
    int cg = (int)threadIdx.x & 3;
    int node = bn + tn;
    if (node >= n) return;
    float4 s0 = make_float4(0.f, 0.f, 0.f, 0.f);
    float4 s1 = make_float4(0.f, 0.f, 0.f, 0.f);
    #pragma unroll 4
    for (int k = 0; k < HDIM; k++) {
        float hv = hbuf[tn][k];
        float4 w0 = *(const float4*)(wo + k * OUTDIM + cg * 8);
        float4 w1 = *(const float4*)(wo + k * OUTDIM + cg * 8 + 4);
        s0.x += hv * w0.x; s0.y += hv * w0.y; s0.z += hv * w0.z; s0.w += hv * w0.w;
        s1.x += hv * w1.x; s1.y += hv * w1.y; s1.z += hv * w1.z; s1.w += hv * w1.w;
    }
    *(float4*)(outp + (size_t)node * OUTDIM + cg * 8) = s0;
    *(float4*)(outp + (size_t)node * OUTDIM + cg * 8 + 4) = s1;
}

// ---------------- agg[d] = rs[d] * sum_{edges} h16[s] + h[d] ----------------
__global__ void aggregate(const __half* __restrict__ h16, const float* __restrict__ hskip,
                          const int* __restrict__ cnt, const int* __restrict__ csr,
                          const float* __restrict__ rs, float* __restrict__ agg, int n) {
    int wave = threadIdx.x >> 6;
    int lane = threadIdx.x & 63;
    int node = blockIdx.x * (blockDim.x >> 6) + wave;
    if (node >= n) return;
    int c = min(cnt[node], CAP);
    int grp = lane >> 4;
    int gl = lane & 15;
    int sl = 0;
    if (lane < c) sl = csr[node * CAP + lane];
    float4 acc0 = make_float4(0.f, 0.f, 0.f, 0.f);
    float4 acc1 = make_float4(0.f, 0.f, 0.f, 0.f);
    int trips = (c + 3) >> 2;
    int i = 0;
    for (; i + 2 <= trips; i += 2) {
        int t0 = 4 * i + grp, t1 = t0 + 4;
        float w0 = (t0 < c) ? 1.f : 0.f;
        float w1 = (t1 < c) ? 1.f : 0.f;
        int u0 = min(t0, c - 1);
        int u1 = min(t1, c - 1);
        int s0 = __shfl(sl, u0);
        int s1 = __shfl(sl, u1);
        uint2 q0 = ((const uint2*)(h16 + (size_t)s0 * HDIM))[gl];
        uint2 q1 = ((const uint2*)(h16 + (size_t)s1 * HDIM))[gl];
        float2 f0a = __half22float2(*(__half2*)&q0.x);
        float2 f0b = __half22float2(*(__half2*)&q0.y);
        float2 f1a = __half22float2(*(__half2*)&q1.x);
        float2 f1b = __half22float2(*(__half2*)&q1.y);
        acc0.x += w0 * f0a.x; acc0.y += w0 * f0a.y;
        acc0.z += w0 * f0b.x; acc0.w += w0 * f0b.y;
        acc1.x += w1 * f1a.x; acc1.y += w1 * f1a.y;
        acc1.z += w1 * f1b.x; acc1.w += w1 * f1b.y;
    }
    if (i < trips) {
        int t = 4 * i + grp;
        float wv = (t < c) ? 1.f : 0.f;
        int u = min(t, c - 1);
        int s = __shfl(sl, u);
        uint2 q = ((const uint2*)(h16 + (size_t)s * HDIM))[gl];
        float2 fa = __half22float2(*(__half2*)&q.x);
        float2 fb = __half22float2(*(__half2*)&q.y);
        acc0.x += wv * fa.x; acc0.y += wv * fa.y;
        acc0.z += wv * fb.x; acc0.w += wv * fb.y;
    }
    acc0.x += acc1.x; acc0.y += acc1.y; acc0.z += acc1.z; acc0.w += acc1.w;
    #pragma unroll
    for (int m = 16; m < 64; m <<= 1) {
        acc0.x += __shfl_xor(acc0.x, m);
        acc0.y += __shfl_xor(acc0.y, m);
        acc0.z += __shfl_xor(acc0.z, m);
        acc0.w += __shfl_xor(acc0.w, m);
    }
    if (grp == 0) {
        float rsd = rs[node];
        float4 sk = ((const float4*)(hskip + (size_t)node * HDIM))[gl];
        acc0.x = acc0.x * rsd + sk.x;
        acc0.y = acc0.y * rsd + sk.y;
        acc0.z = acc0.z * rsd + sk.z;
        acc0.w = acc0.w * rsd + sk.w;
        ((float4*)(agg + (size_t)node * HDIM))[gl] = acc0;
    }
}

extern "C" void kernel_launch(void* const* d_in, const int* in_sizes, int n_in,
                              void* d_out, int out_size, void* d_ws, size_t ws_size,
                              hipStream_t stream) {
    const float* x    = (const float*)d_in[0];
    const int*   ei   = (const int*)d_in[1];
    const float* Win  = (const float*)d_in[2];
    const float* Wl   = (const float*)d_in[3];
    const float* Wout = (const float*)d_in[4];
    float* out = (float*)d_out;

    int n = in_sizes[0] / INDIM;   // 100000
    int e = in_sizes[1] / 2;       // 1600000
    const int* dst = ei;           // edge_index[0]
    const int* src = ei + e;       // edge_index[1]

    int nb = (n + BNODES - 1) / BNODES;   // 782 buckets

    // workspace: gcur | cnt | rs | binned | csr_pad | h | agg | h16a | h16b
    char* w = (char*)d_ws;
    int* gcur = (int*)w;      w += 1024 * 4;
    int* cnt = (int*)w;       w += (size_t)n * 4;
    float* rs = (float*)w;    w += (size_t)n * 4;
    w = (char*)(((uintptr_t)w + 255) & ~(uintptr_t)255);
    int* binned = (int*)w;    w += (size_t)nb * BCAP * 4;          // 7.2 MB
    int* csr = (int*)w;       w += (size_t)nb * BNODES * CAP * 4;  // 25.6 MB
    float* h = (float*)w;     w += (size_t)n * HDIM * 4;           // 25.6 MB
    float* agg = (float*)w;   w += (size_t)n * HDIM * 4;           // 25.6 MB
    __half* h16a = (__half*)w; w += (size_t)n * HDIM * 2;          // 12.8 MB
    __half* h16b = (__half*)w; w += (size_t)n * HDIM * 2;          // 12.8 MB

    hipMemsetAsync(gcur, 0, 1024 * 4, stream);

    // two-phase padded-CSR build
    int ablocks = (e + EPB - 1) / EPB;    // 391
    bin_edges<<<ablocks, 256, 0, stream>>>(dst, src, gcur, binned, e, nb);
    build_csr<<<nb, 256, 0, stream>>>(gcur, binned, cnt, rs, csr, n);

    int g128 = (n + 127) / 128;   // 782 blocks at BM=128
    // h = x @ W_in  (+ rs-scaled fp16 shadow h16a)
    gemm_node<INDIM, HDIM, 128, 512, false, true><<<g128, 512, 0, stream>>>(
        x, Win, h, h16a, rs, n);

    // layer 0: agg = rs*(sum h16a) + h;  h = relu(agg @ W0) (+ shadow h16b)
    aggregate<<<(n + 3) / 4, 256, 0, stream>>>(h16a, h, cnt, csr, rs, agg, n);
    gemm_node<HDIM, HDIM, 128, 512, true, true><<<g128, 512, 0, stream>>>(
        agg, Wl, h, h16b, rs, n);

    // layer 1 fused with output: agg = rs*(sum h16b) + h;
    // out = relu(agg @ W1) @ Wout
    aggregate<<<(n + 3) / 4, 256, 0, stream>>>(h16b, h, cnt, csr, rs, agg, n);
    gemm_layer_out<<<g128, 512, 0, stream>>>(agg, Wl + (size_t)HDIM * HDIM,
                                             Wout, out, n);
}